// Round 1
// baseline (1153.669 us; speedup 1.0000x reference)
//
#include <hip/hip_runtime.h>
#include <math.h>

// Problem constants (match reference setup_inputs)
constexpr int Bc = 64, Nc = 2048, Dc = 512, Hc = 512;
constexpr long long Mc = (long long)Bc * Nc;   // 131072 rows
constexpr int BM = 128, BN = 128, BK = 16;
constexpr int LDT = 132;                        // padded LDS leading dim (floats)

// ---------------------------------------------------------------------------
// GEMM: Hout[M][H] = X[M][D] @ W[D][H] + bias   (fp32, vector FMA)
// 256 threads, 8x8 micro-tile per thread, waves arranged 2x2, lanes 8x8.
// ---------------------------------------------------------------------------
__global__ __launch_bounds__(256) void gemm_bias(const float* __restrict__ X,
                                                 const float* __restrict__ W,
                                                 const float* __restrict__ bias,
                                                 float* __restrict__ Hout)
{
    __shared__ float As[BK][LDT];   // [k][m] transposed A tile
    __shared__ float Bs[BK][LDT];   // [k][n]

    const int tid = threadIdx.x;
    const int bn = blockIdx.x;          // 0..3   (N blocks; consecutive blocks share A tile in L2)
    const int bm = blockIdx.y;          // 0..1023
    const int m0 = bm * BM, n0 = bn * BN;

    const int wave = tid >> 6, lane = tid & 63;
    const int wm = wave >> 1, wn = wave & 1;
    const int lm = lane >> 3, ln = lane & 7;
    const int am = wm * 64 + lm * 8;    // row offset within tile
    const int an = wn * 64 + ln * 8;    // col offset within tile

    // staging maps
    const int ar0 = tid >> 2;                 // 0..63 (second load = +64)
    const int ak0 = (tid & 3) * 4;            // k quad
    const int br0 = tid >> 5;                 // 0..7  (second load = +8)
    const int bq0 = (tid & 31) * 4;           // n quad

    const float* aBase = X + (size_t)(m0 + ar0) * Dc + ak0;
    const float* bBase = W + (size_t)br0 * Hc + n0 + bq0;

    float acc[8][8];
#pragma unroll
    for (int i = 0; i < 8; ++i)
#pragma unroll
        for (int j = 0; j < 8; ++j) acc[i][j] = 0.0f;

    // prefetch first tile into registers
    float4 av0 = *(const float4*)(aBase);
    float4 av1 = *(const float4*)(aBase + (size_t)64 * Dc);
    float4 bv0 = *(const float4*)(bBase);
    float4 bv1 = *(const float4*)(bBase + (size_t)8 * Hc);

    for (int kt = 0; kt < Dc; kt += BK) {
        __syncthreads();
        // A transpose-write (2-way bank aliasing max thanks to LDT=132 pad)
        As[ak0 + 0][ar0] = av0.x;  As[ak0 + 1][ar0] = av0.y;
        As[ak0 + 2][ar0] = av0.z;  As[ak0 + 3][ar0] = av0.w;
        As[ak0 + 0][ar0 + 64] = av1.x;  As[ak0 + 1][ar0 + 64] = av1.y;
        As[ak0 + 2][ar0 + 64] = av1.z;  As[ak0 + 3][ar0 + 64] = av1.w;
        *(float4*)&Bs[br0][bq0]     = bv0;
        *(float4*)&Bs[br0 + 8][bq0] = bv1;
        __syncthreads();

        const int kn = kt + BK;
        if (kn < Dc) {   // prefetch next tile; latency hides under the FMAs below
            av0 = *(const float4*)(aBase + kn);
            av1 = *(const float4*)(aBase + (size_t)64 * Dc + kn);
            bv0 = *(const float4*)(bBase + (size_t)kn * Hc);
            bv1 = *(const float4*)(bBase + (size_t)(kn + 8) * Hc);
        }

#pragma unroll
        for (int k = 0; k < BK; ++k) {
            float4 a0 = *(const float4*)&As[k][am];
            float4 a1 = *(const float4*)&As[k][am + 4];
            float4 b0 = *(const float4*)&Bs[k][an];
            float4 b1 = *(const float4*)&Bs[k][an + 4];
            float a_[8] = {a0.x, a0.y, a0.z, a0.w, a1.x, a1.y, a1.z, a1.w};
            float b_[8] = {b0.x, b0.y, b0.z, b0.w, b1.x, b1.y, b1.z, b1.w};
#pragma unroll
            for (int i = 0; i < 8; ++i)
#pragma unroll
                for (int j = 0; j < 8; ++j)
                    acc[i][j] = fmaf(a_[i], b_[j], acc[i][j]);
        }
    }

    // epilogue: + bias, store
    float4 c0 = *(const float4*)&bias[n0 + an];
    float4 c1 = *(const float4*)&bias[n0 + an + 4];
#pragma unroll
    for (int i = 0; i < 8; ++i) {
        const size_t row = (size_t)(m0 + am + i);
        float4 o0, o1;
        o0.x = acc[i][0] + c0.x; o0.y = acc[i][1] + c0.y;
        o0.z = acc[i][2] + c0.z; o0.w = acc[i][3] + c0.w;
        o1.x = acc[i][4] + c1.x; o1.y = acc[i][5] + c1.y;
        o1.z = acc[i][6] + c1.z; o1.w = acc[i][7] + c1.w;
        *(float4*)&Hout[row * Hc + n0 + an]     = o0;
        *(float4*)&Hout[row * Hc + n0 + an + 4] = o1;
    }
}

// ---------------------------------------------------------------------------
// Column stats: fp32 partials over 256-row chunks -> fp64 atomics
// ---------------------------------------------------------------------------
__global__ __launch_bounds__(256) void zero_stats(double* __restrict__ s)
{
    int i = blockIdx.x * 256 + threadIdx.x;
    if (i < 1024) s[i] = 0.0;
}

__global__ __launch_bounds__(256) void colstats(const float* __restrict__ Hbuf,
                                                double* __restrict__ sum,
                                                double* __restrict__ sumsq)
{
    const int c = threadIdx.x;                 // columns c and c+256
    const long long r0 = (long long)blockIdx.x * 256;
    float s0 = 0.f, q0 = 0.f, s1 = 0.f, q1 = 0.f;
    for (long long r = r0; r < r0 + 256; ++r) {
        float v0 = Hbuf[(size_t)r * Hc + c];
        float v1 = Hbuf[(size_t)r * Hc + c + 256];
        s0 += v0; q0 = fmaf(v0, v0, q0);
        s1 += v1; q1 = fmaf(v1, v1, q1);
    }
    atomicAdd(&sum[c], (double)s0);
    atomicAdd(&sumsq[c], (double)q0);
    atomicAdd(&sum[c + 256], (double)s1);
    atomicAdd(&sumsq[c + 256], (double)q1);
}

__global__ __launch_bounds__(256) void finalize_stats(const double* __restrict__ sum,
                                                      const double* __restrict__ sumsq,
                                                      const float* __restrict__ gamma,
                                                      const float* __restrict__ beta,
                                                      float* __restrict__ scale,
                                                      float* __restrict__ shift)
{
    int c = blockIdx.x * 256 + threadIdx.x;
    if (c < Hc) {
        double mu  = sum[c] / (double)Mc;
        double var = sumsq[c] / (double)Mc - mu * mu;
        double rstd = 1.0 / sqrt(var + 1e-5);
        float a = (float)rstd * gamma[c];
        scale[c] = a;
        shift[c] = beta[c] - (float)mu * a;
    }
}

// ---------------------------------------------------------------------------
// Head: one wave per (b, pos). normalize+relu h row, dot with W[C], argmax.
// Templated on C so p[] stays in registers (runtime-indexed arrays spill).
// ---------------------------------------------------------------------------
template <int C>
__global__ __launch_bounds__(256) void head_kernel(const float* __restrict__ Hbuf,
                                                   const float* __restrict__ scale,
                                                   const float* __restrict__ shift,
                                                   const float* __restrict__ W,
                                                   const float* __restrict__ bias,
                                                   const int* __restrict__ idx,
                                                   float* __restrict__ out)
{
    const long long wid = ((long long)blockIdx.x * blockDim.x + threadIdx.x) >> 6;
    const int lane = threadIdx.x & 63;
    if (wid >= (long long)Bc * (Nc / 2)) return;
    const int b   = (int)(wid >> 10);          // / 1024
    const int pos = (int)(wid & 1023);
    const int n   = idx[pos];
    const size_t row = (size_t)b * Nc + n;

    const int i0 = lane * 8;
    float4 h0 = *(const float4*)&Hbuf[row * Hc + i0];
    float4 h1 = *(const float4*)&Hbuf[row * Hc + i0 + 4];
    float4 s0 = *(const float4*)&scale[i0];
    float4 s1 = *(const float4*)&scale[i0 + 4];
    float4 t0 = *(const float4*)&shift[i0];
    float4 t1 = *(const float4*)&shift[i0 + 4];

    float v[8];
    v[0] = fmaxf(fmaf(h0.x, s0.x, t0.x), 0.f);
    v[1] = fmaxf(fmaf(h0.y, s0.y, t0.y), 0.f);
    v[2] = fmaxf(fmaf(h0.z, s0.z, t0.z), 0.f);
    v[3] = fmaxf(fmaf(h0.w, s0.w, t0.w), 0.f);
    v[4] = fmaxf(fmaf(h1.x, s1.x, t1.x), 0.f);
    v[5] = fmaxf(fmaf(h1.y, s1.y, t1.y), 0.f);
    v[6] = fmaxf(fmaf(h1.z, s1.z, t1.z), 0.f);
    v[7] = fmaxf(fmaf(h1.w, s1.w, t1.w), 0.f);

    float p[C];
#pragma unroll
    for (int c = 0; c < C; ++c) p[c] = 0.f;
#pragma unroll
    for (int u = 0; u < 8; ++u) {
        const float* wrow = W + (size_t)(i0 + u) * C;
#pragma unroll
        for (int c = 0; c < C; ++c) p[c] = fmaf(v[u], wrow[c], p[c]);
    }
#pragma unroll
    for (int off = 32; off; off >>= 1)
#pragma unroll
        for (int c = 0; c < C; ++c) p[c] += __shfl_xor(p[c], off);

    if (lane == 0) {
        float best = p[0] + bias[0];
        int bi = 0;
#pragma unroll
        for (int c = 1; c < C; ++c) {
            float l = p[c] + bias[c];
            if (l > best) { best = l; bi = c; }   // strict > : first-index tie-break, matches jnp.argmax
        }
        out[row] = (float)bi;
    }
}

// ---------------------------------------------------------------------------
extern "C" void kernel_launch(void* const* d_in, const int* in_sizes, int n_in,
                              void* d_out, int out_size, void* d_ws, size_t ws_size,
                              hipStream_t stream)
{
    (void)in_sizes; (void)n_in; (void)out_size; (void)ws_size;
    const float* x     = (const float*)d_in[0];
    const float* W1    = (const float*)d_in[1];
    const float* b1    = (const float*)d_in[2];
    const float* gamma = (const float*)d_in[3];
    const float* beta  = (const float*)d_in[4];
    const float* Wa    = (const float*)d_in[5];
    const float* ba    = (const float*)d_in[6];
    const float* Wb    = (const float*)d_in[7];
    const float* bb    = (const float*)d_in[8];
    const int*   idx_a = (const int*)d_in[9];
    const int*   idx_b = (const int*)d_in[10];
    float* out = (float*)d_out;

    char* ws = (char*)d_ws;
    float*  Hbuf  = (float*)ws;                                  // 131072*512*4 = 256 MiB
    double* sums  = (double*)(ws + (size_t)Mc * Hc * 4);         // 1024 doubles (sum | sumsq)
    float*  scale = (float*)((char*)sums + 1024 * sizeof(double));
    float*  shift = scale + Hc;

    zero_stats<<<4, 256, 0, stream>>>(sums);
    gemm_bias<<<dim3(4, 1024), 256, 0, stream>>>(x, W1, b1, Hbuf);
    colstats<<<512, 256, 0, stream>>>(Hbuf, sums, sums + 512);
    finalize_stats<<<2, 256, 0, stream>>>(sums, sums + 512, gamma, beta, scale, shift);

    const long long waves_half = (long long)Bc * (Nc / 2);       // 65536
    const int blocks_half = (int)((waves_half * 64 + 255) / 256); // 16384
    head_kernel<3><<<blocks_half, 256, 0, stream>>>(Hbuf, scale, shift, Wa, ba, idx_a, out);
    head_kernel<5><<<blocks_half, 256, 0, stream>>>(Hbuf, scale, shift, Wb, bb, idx_b, out);
}